// Round 2
// baseline (5262.938 us; speedup 1.0000x reference)
//
#include <hip/hip_runtime.h>
#include <cstddef>

// Problem constants (fixed by the reference)
static const int WW = 8192;     // width (atoms)
static const int DD = 768;      // input dim
static const int BBATCH = 8192; // batch
static const int KSEL = 32;     // MP steps

typedef double f64x4 __attribute__((ext_vector_type(4)));

// ---------------------------------------------------------------------------
// Runtime probe of the v_mfma_f64_16x16x4 D-fragment wiring.
// Assumes only the INPUT mappings (A: i=lane%16,k=lane/16; B: j=lane%16,
// k=lane/16 — the CK/xdlops-standard ones). With a = lane, B = all-ones:
//   d1[v] = sum_k A[i][k] = sum_k (i + 16k) = 4*i + 96   -> decode i(lane,v)
// With A = all-ones, b = lane:
//   d2[v] = sum_k B[k][j] = 4*j + 96                     -> decode j(lane,v)
// This is correct for ANY output wiring (contiguous / interleaved /
// transposed). Decoded indices are clamped to [0,15] so a broken assumption
// cannot write out of bounds.
// ---------------------------------------------------------------------------
__device__ inline void mfma_f64_probe(int lane, int* pi, int* pj) {
    f64x4 z0{0.0, 0.0, 0.0, 0.0};
    f64x4 d1 = __builtin_amdgcn_mfma_f64_16x16x4f64((double)lane, 1.0, z0, 0, 0, 0);
    f64x4 d2 = __builtin_amdgcn_mfma_f64_16x16x4f64(1.0, (double)lane, z0, 0, 0, 0);
#pragma unroll
    for (int v = 0; v < 4; ++v) {
        pi[v] = (((int)d1[v] - 96) >> 2) & 15;
        pj[v] = (((int)d2[v] - 96) >> 2) & 15;
    }
}

// ---------------------------------------------------------------------------
// column norms of Ad [D, W] -> nrm[W] = max(||Ad[:,w]||, 1e-8), fp64 accumulate
// ---------------------------------------------------------------------------
__global__ __launch_bounds__(256) void colnorm_kernel(const float* __restrict__ Ad,
                                                      float* __restrict__ nrm) {
    int w = blockIdx.x * 256 + threadIdx.x;
    double s = 0.0;
    for (int d = 0; d < DD; ++d) {
        double v = (double)Ad[(size_t)d * WW + w];
        s += v * v;
    }
    nrm[w] = fmaxf((float)sqrt(s), 1e-8f);
}

// ---------------------------------------------------------------------------
// AdnT[w, d] = Ad[d, w] / nrm[w]   (LDS tiled transpose, 32x32)
// ---------------------------------------------------------------------------
__global__ __launch_bounds__(256) void transpose_scale_kernel(const float* __restrict__ Ad,
                                                              const float* __restrict__ nrm,
                                                              float* __restrict__ AdnT) {
    __shared__ float tile[32][33];
    int wb = blockIdx.x * 32;
    int db = blockIdx.y * 32;
    int tx = threadIdx.x;   // 0..31
    int ty = threadIdx.y;   // 0..7
    for (int i = ty; i < 32; i += 8)
        tile[i][tx] = Ad[(size_t)(db + i) * WW + (wb + tx)];
    __syncthreads();
    for (int i = ty; i < 32; i += 8)
        AdnT[(size_t)(wb + i) * DD + (db + tx)] = tile[tx][i] / nrm[wb + i];
}

// ---------------------------------------------------------------------------
// Gram via f64 MFMA: G[i,j] = (sum_d Ad[d,i]*Ad[d,j]) / (nrm[i]*nrm[j])
// 128x128 block, 4 waves (2x2), each wave 4x4 tiles of v_mfma_f64_16x16x4.
// BK=16; panels staged f32->f64 into LDS (lane-contiguous double2, conflict-
// free). Next K-panel prefetched into registers before the inner loop.
// Upper blocks only (by <= bx); mirror fills strict-lower 64-tiles.
// Output placement comes from the runtime probe (pi/pj), not an assumed map.
// ---------------------------------------------------------------------------
__global__ __launch_bounds__(256) void gram_mfma_f64_kernel(const float* __restrict__ Ad,
                                                            const float* __restrict__ nrm,
                                                            float* __restrict__ G) {
    const int bx = blockIdx.x, by = blockIdx.y;
    if (by > bx) return;   // block entirely strictly-lower -> skip (mirror fills)
    __shared__ __align__(16) double As[16 * 130];   // As[k][i], i=0..127
    __shared__ __align__(16) double Bs[16 * 130];   // Bs[k][j], j=0..127
    const int tid = threadIdx.x;
    const int lane = tid & 63;
    const int wv = tid >> 6;        // wave 0..3
    const int wr = wv >> 1;         // 0..1 row half
    const int wc = wv & 1;          // 0..1 col half
    const int i0 = by * 128;
    const int j0 = bx * 128;
    // staging: slot q (0..3): row 4q+ar0, pos ap0 (lane-contiguous double2)
    const int ar0 = tid >> 6;        // 0..3
    const int ap0 = (tid & 63) * 2;  // 0..126

    int pi[4], pj[4];
    mfma_f64_probe(lane, pi, pj);

    f64x4 acc[4][4];
#pragma unroll
    for (int m = 0; m < 4; ++m)
#pragma unroll
        for (int n = 0; n < 4; ++n)
            acc[m][n] = f64x4{0.0, 0.0, 0.0, 0.0};

    float2 aL[4], bL[4];
#pragma unroll
    for (int q = 0; q < 4; ++q) {
        aL[q] = *(const float2*)&Ad[(size_t)(4 * q + ar0) * WW + i0 + ap0];
        bL[q] = *(const float2*)&Ad[(size_t)(4 * q + ar0) * WW + j0 + ap0];
    }

    for (int k0 = 0; k0 < DD; k0 += 16) {
        __syncthreads();   // previous iteration's LDS reads done
#pragma unroll
        for (int q = 0; q < 4; ++q) {
            double2 da; da.x = (double)aL[q].x; da.y = (double)aL[q].y;
            *(double2*)&As[(4 * q + ar0) * 130 + ap0] = da;
            double2 db; db.x = (double)bL[q].x; db.y = (double)bL[q].y;
            *(double2*)&Bs[(4 * q + ar0) * 130 + ap0] = db;
        }
        __syncthreads();
        if (k0 + 16 < DD) {   // prefetch next panel; latency hides under MFMAs
#pragma unroll
            for (int q = 0; q < 4; ++q) {
                aL[q] = *(const float2*)&Ad[(size_t)(k0 + 16 + 4 * q + ar0) * WW + i0 + ap0];
                bL[q] = *(const float2*)&Ad[(size_t)(k0 + 16 + 4 * q + ar0) * WW + j0 + ap0];
            }
        }
#pragma unroll
        for (int kc = 0; kc < 4; ++kc) {
            const int krow = kc * 4 + (lane >> 4);
            const double* ap = &As[krow * 130 + wr * 64 + (lane & 15)];
            const double* bp = &Bs[krow * 130 + wc * 64 + (lane & 15)];
            double aF[4], bF[4];
#pragma unroll
            for (int m = 0; m < 4; ++m) aF[m] = ap[m * 16];
#pragma unroll
            for (int n = 0; n < 4; ++n) bF[n] = bp[n * 16];
#pragma unroll
            for (int m = 0; m < 4; ++m)
#pragma unroll
                for (int n = 0; n < 4; ++n)
                    acc[m][n] = __builtin_amdgcn_mfma_f64_16x16x4f64(aF[m], bF[n],
                                                                     acc[m][n], 0, 0, 0);
        }
    }

#pragma unroll
    for (int m = 0; m < 4; ++m) {
#pragma unroll
        for (int v = 0; v < 4; ++v) {
            int row = i0 + wr * 64 + m * 16 + pi[v];
            double inv_i = 1.0 / (double)nrm[row];
#pragma unroll
            for (int n = 0; n < 4; ++n) {
                int col = j0 + wc * 64 + n * 16 + pj[v];
                G[(size_t)row * WW + col] = (float)(acc[m][n][v] * inv_i / (double)nrm[col]);
            }
        }
    }
}

// ---------------------------------------------------------------------------
// mirror: G[j,i] = G[i,j] for strict-upper 64x64 tiles
// ---------------------------------------------------------------------------
__global__ __launch_bounds__(256) void mirror_kernel(float* __restrict__ G) {
    const int ti = blockIdx.y;
    const int tj = blockIdx.x;
    if (tj <= ti) return;
    __shared__ float tile[64][65];
    const int t = threadIdx.x;
    const int c4 = (t & 15) * 4;   // 0..60
    const int r  = t >> 4;         // 0..15
#pragma unroll
    for (int rr = r; rr < 64; rr += 16) {
        float4 v = *(const float4*)&G[(size_t)(ti * 64 + rr) * WW + tj * 64 + c4];
        tile[rr][c4 + 0] = v.x;
        tile[rr][c4 + 1] = v.y;
        tile[rr][c4 + 2] = v.z;
        tile[rr][c4 + 3] = v.w;
    }
    __syncthreads();
#pragma unroll
    for (int rr = r; rr < 64; rr += 16) {
        float4 v = make_float4(tile[c4 + 0][rr], tile[c4 + 1][rr],
                               tile[c4 + 2][rr], tile[c4 + 3][rr]);
        *(float4*)&G[(size_t)(tj * 64 + rr) * WW + ti * 64 + c4] = v;
    }
}

// ---------------------------------------------------------------------------
// z via f64 MFMA: Z[b,w] = (sum_d (X[b,d]-bd[d]) * Ad[d,w]) / nrm[w]
// 64x128 block, 4 waves (1x4), each wave 4x2 tiles. A staged transposed
// As[k][b] f64 (scalar b64 writes), B staged double2-contiguous. Prefetch
// before the inner loop. f32 bias subtract then exact f64 promotion.
// Output placement from the runtime probe (pi/pj).
// ---------------------------------------------------------------------------
__global__ __launch_bounds__(256) void z_mfma_f64_kernel(const float* __restrict__ X,
                                                         const float* __restrict__ Ad,
                                                         const float* __restrict__ bd,
                                                         const float* __restrict__ nrm,
                                                         float* __restrict__ Z) {
    __shared__ __align__(16) double As[16 * 66];    // As[k][b], b=0..63
    __shared__ __align__(16) double Bs[16 * 130];   // Bs[k][w], w=0..127
    const int tid = threadIdx.x;
    const int lane = tid & 63;
    const int wc = tid >> 6;        // wave 0..3 -> 32-col group
    const int b0 = blockIdx.y * 64;
    const int w0 = blockIdx.x * 128;
    // A staging: r = tid>>2 (0..63) batch row, k4 = (tid&3)*4 k offset
    const int r  = tid >> 2;
    const int k4 = (tid & 3) * 4;
    // B staging: slot q: row 4q+br0, pos bp0 (lane-contiguous double2)
    const int br0 = tid >> 6;
    const int bp0 = (tid & 63) * 2;

    int pi[4], pj[4];
    mfma_f64_probe(lane, pi, pj);

    f64x4 acc[4][2];
#pragma unroll
    for (int m = 0; m < 4; ++m)
#pragma unroll
        for (int n = 0; n < 2; ++n)
            acc[m][n] = f64x4{0.0, 0.0, 0.0, 0.0};

    float4 aL; float2 bL[4];
    {
        float4 bias = *(const float4*)&bd[k4];
        float4 a = *(const float4*)&X[(size_t)(b0 + r) * DD + k4];
        a.x -= bias.x; a.y -= bias.y; a.z -= bias.z; a.w -= bias.w;
        aL = a;
#pragma unroll
        for (int q = 0; q < 4; ++q)
            bL[q] = *(const float2*)&Ad[(size_t)(4 * q + br0) * WW + w0 + bp0];
    }

    for (int k0 = 0; k0 < DD; k0 += 16) {
        __syncthreads();   // previous iteration's LDS reads done
        As[(k4 + 0) * 66 + r] = (double)aL.x;
        As[(k4 + 1) * 66 + r] = (double)aL.y;
        As[(k4 + 2) * 66 + r] = (double)aL.z;
        As[(k4 + 3) * 66 + r] = (double)aL.w;
#pragma unroll
        for (int q = 0; q < 4; ++q) {
            double2 db; db.x = (double)bL[q].x; db.y = (double)bL[q].y;
            *(double2*)&Bs[(4 * q + br0) * 130 + bp0] = db;
        }
        __syncthreads();
        if (k0 + 16 < DD) {
            const int kn = k0 + 16;
            float4 bias = *(const float4*)&bd[kn + k4];
            float4 a = *(const float4*)&X[(size_t)(b0 + r) * DD + kn + k4];
            a.x -= bias.x; a.y -= bias.y; a.z -= bias.z; a.w -= bias.w;
            aL = a;
#pragma unroll
            for (int q = 0; q < 4; ++q)
                bL[q] = *(const float2*)&Ad[(size_t)(kn + 4 * q + br0) * WW + w0 + bp0];
        }
#pragma unroll
        for (int kc = 0; kc < 4; ++kc) {
            const int krow = kc * 4 + (lane >> 4);
            const double* ap = &As[krow * 66 + (lane & 15)];
            const double* bp = &Bs[krow * 130 + wc * 32 + (lane & 15)];
            double aF[4], bF[2];
#pragma unroll
            for (int m = 0; m < 4; ++m) aF[m] = ap[m * 16];
#pragma unroll
            for (int n = 0; n < 2; ++n) bF[n] = bp[n * 16];
#pragma unroll
            for (int m = 0; m < 4; ++m)
#pragma unroll
                for (int n = 0; n < 2; ++n)
                    acc[m][n] = __builtin_amdgcn_mfma_f64_16x16x4f64(aF[m], bF[n],
                                                                     acc[m][n], 0, 0, 0);
        }
    }

#pragma unroll
    for (int m = 0; m < 4; ++m) {
#pragma unroll
        for (int v = 0; v < 4; ++v) {
            int row = b0 + m * 16 + pi[v];
#pragma unroll
            for (int n = 0; n < 2; ++n) {
                int col = w0 + wc * 32 + n * 16 + pj[v];
                Z[(size_t)row * WW + col] = (float)(acc[m][n][v] / (double)nrm[col]);
            }
        }
    }
}

// ---------------------------------------------------------------------------
// Fused MP loop. One block per batch row; z-row in LDS for all 32 steps.
// ---------------------------------------------------------------------------
__global__ __launch_bounds__(256) void mp_loop_kernel(const float* __restrict__ z0,
                                                      const float* __restrict__ G,
                                                      int* __restrict__ idxL,
                                                      float* __restrict__ valL) {
    __shared__ __align__(16) float zrow[WW];   // 32 KB
    __shared__ float wv[4];
    __shared__ int   wi[4];
    const int b = blockIdx.x;
    const int t = threadIdx.x;
    float4* zs = (float4*)zrow;

    float best = -1.f;
    int bidx = 0;
    unsigned selmask = 0;   // bit j*4+e: slot (t+256*j) element e is selected

    {
        const float4* zp = (const float4*)(z0 + (size_t)b * WW);
#pragma unroll
        for (int j = 0; j < 8; ++j) {
            int slot = t + 256 * j;
            float4 v = zp[slot];
            zs[slot] = v;
            int w = slot * 4;
            float a0 = fabsf(v.x), a1 = fabsf(v.y), a2 = fabsf(v.z), a3 = fabsf(v.w);
            if (a0 > best) { best = a0; bidx = w; }
            if (a1 > best) { best = a1; bidx = w + 1; }
            if (a2 > best) { best = a2; bidx = w + 2; }
            if (a3 > best) { best = a3; bidx = w + 3; }
        }
    }

    for (int k = 0; k < KSEL; ++k) {
        float v = best;
        int i = bidx;
#pragma unroll
        for (int off = 32; off > 0; off >>= 1) {
            float ov = __shfl_xor(v, off, 64);
            int   oi = __shfl_xor(i, off, 64);
            if (ov > v || (ov == v && oi < i)) { v = ov; i = oi; }
        }
        if ((t & 63) == 0) { wv[t >> 6] = v; wi[t >> 6] = i; }
        __syncthreads();   // A: partials visible; prev phase's zrow writes visible
        float rv = wv[0];
        int   ri = wi[0];
#pragma unroll
        for (int q = 1; q < 4; ++q) {
            float qv = wv[q];
            int   qi = wi[q];
            if (qv > rv || (qv == rv && qi < ri)) { rv = qv; ri = qi; }
        }
        const int idx = ri;
        const float val = zrow[idx];   // pre-update value (LDS broadcast)
        if (t == 0) {
            idxL[(size_t)b * KSEL + k] = idx;
            valL[(size_t)b * KSEL + k] = val;
        }
        if (((idx >> 2) & 255) == t)
            selmask |= 1u << (((idx >> 10) << 2) | (idx & 3));
        if (k == KSEL - 1) break;      // final update is dead work
        __syncthreads();   // B: all threads have read val before zrow changes

        best = -1.f;
        bidx = 0;
        const float4* gr = (const float4*)(G + (size_t)idx * WW);
#pragma unroll
        for (int j = 0; j < 8; ++j) {
            int slot = t + 256 * j;
            float4 g = gr[slot];
            float4 z = zs[slot];
            unsigned m = (selmask >> (j * 4)) & 0xFu;
            float n0 = (m & 1u) ? 0.f : z.x - val * g.x;
            float n1 = (m & 2u) ? 0.f : z.y - val * g.y;
            float n2 = (m & 4u) ? 0.f : z.z - val * g.z;
            float n3 = (m & 8u) ? 0.f : z.w - val * g.w;
            zs[slot] = make_float4(n0, n1, n2, n3);
            int w = slot * 4;
            float a0 = fabsf(n0), a1 = fabsf(n1), a2 = fabsf(n2), a3 = fabsf(n3);
            if (a0 > best) { best = a0; bidx = w; }
            if (a1 > best) { best = a1; bidx = w + 1; }
            if (a2 > best) { best = a2; bidx = w + 2; }
            if (a3 > best) { best = a3; bidx = w + 3; }
        }
    }
}

// ---------------------------------------------------------------------------
// copy idx/val metadata (d_out staging -> ws), element-wise
// ---------------------------------------------------------------------------
__global__ __launch_bounds__(256) void copy_meta_kernel(const int* __restrict__ si,
                                                        const float* __restrict__ sv,
                                                        int* __restrict__ di,
                                                        float* __restrict__ dv,
                                                        int n) {
    int i = blockIdx.x * 256 + threadIdx.x;
    if (i < n) {
        di[i] = si[i];
        dv[i] = sv[i];
    }
}

// ---------------------------------------------------------------------------
// out[row, :] = bd + sum_k val[b,k] * AdnT[idx[b,k], :]
// ---------------------------------------------------------------------------
__global__ __launch_bounds__(256) void assemble_kernel(const float* __restrict__ AdnT,
                                                       const float* __restrict__ bd,
                                                       const int* __restrict__ idxL,
                                                       const float* __restrict__ valL,
                                                       float* __restrict__ out,
                                                       int rowStart) {
    __shared__ int sidx[KSEL];
    __shared__ float sval[KSEL];
    const int b = blockIdx.x;
    const int row = rowStart + b;
    const int t = threadIdx.x;
    if (t < KSEL) {
        sidx[t] = idxL[(size_t)b * KSEL + t];
        sval[t] = valL[(size_t)b * KSEL + t];
    }
    __syncthreads();
    float acc0 = bd[t];
    float acc1 = bd[t + 256];
    float acc2 = bd[t + 512];
#pragma unroll 4
    for (int k = 0; k < KSEL; ++k) {
        const float* col = AdnT + (size_t)sidx[k] * DD;
        float v = sval[k];
        acc0 += v * col[t];
        acc1 += v * col[t + 256];
        acc2 += v * col[t + 512];
    }
    out[(size_t)row * DD + t] = acc0;
    out[(size_t)row * DD + t + 256] = acc1;
    out[(size_t)row * DD + t + 512] = acc2;
}

// ---------------------------------------------------------------------------
extern "C" void kernel_launch(void* const* d_in, const int* in_sizes, int n_in,
                              void* d_out, int out_size, void* d_ws, size_t ws_size,
                              hipStream_t stream) {
    const float* x  = (const float*)d_in[0];   // [B, D]
    const float* Ad = (const float*)d_in[1];   // [D, W]
    const float* bd = (const float*)d_in[2];   // [1, D]
    float* out = (float*)d_out;                // [B, D]

    const size_t ADNT_B = (size_t)WW * DD * 4;        // 25,165,824
    const size_t NRM_B  = (size_t)WW * 4;             // 32,768
    const size_t IDX_B  = (size_t)BBATCH * KSEL * 4;  // 1,048,576
    const size_t VAL_B  = IDX_B;
    const size_t G_B    = (size_t)WW * WW * 4;        // 268,435,456 (= 256 MiB)
    const size_t ZROW_B = (size_t)WW * 4;             // 32,768
    const size_t A_MIN  = ADNT_B + NRM_B + IDX_B + VAL_B + G_B + 128 * ZROW_B;

    if (ws_size >= A_MIN) {
        // ---------------- Layout A: everything in ws ----------------
        char* p = (char*)d_ws;
        float* AdnT = (float*)p;  p += ADNT_B;
        float* nrm  = (float*)p;  p += NRM_B;
        int*   idxL = (int*)p;    p += IDX_B;
        float* valL = (float*)p;  p += VAL_B;
        float* G    = (float*)p;  p += G_B;
        float* z    = (float*)p;
        size_t z_avail = ws_size - (ADNT_B + NRM_B + IDX_B + VAL_B + G_B);
        int chunk = (int)((z_avail / ZROW_B) / 128) * 128;
        if (chunk > BBATCH) chunk = BBATCH;

        colnorm_kernel<<<WW / 256, 256, 0, stream>>>(Ad, nrm);
        gram_mfma_f64_kernel<<<dim3(WW / 128, WW / 128), 256, 0, stream>>>(Ad, nrm, G);
        mirror_kernel<<<dim3(WW / 64, WW / 64), 256, 0, stream>>>(G);
        for (int r0 = 0; r0 < BBATCH; r0 += chunk) {
            int rows = (BBATCH - r0 < chunk) ? (BBATCH - r0) : chunk;
            z_mfma_f64_kernel<<<dim3(WW / 128, rows / 64), 256, 0, stream>>>(
                x + (size_t)r0 * DD, Ad, bd, nrm, z);
            mp_loop_kernel<<<rows, 256, 0, stream>>>(
                z, G, idxL + (size_t)r0 * KSEL, valL + (size_t)r0 * KSEL);
        }
        transpose_scale_kernel<<<dim3(WW / 32, DD / 32), dim3(32, 8), 0, stream>>>(Ad, nrm, AdnT);
        assemble_kernel<<<BBATCH, 256, 0, stream>>>(AdnT, bd, idxL, valL, out, 0);
    } else if (ws_size >= G_B) {
        // ---------------- Layout B: ws = G only; scratch in d_out ----------------
        float* G    = (float*)d_ws;
        char*  ob   = (char*)d_out;
        float* z    = (float*)ob;
        float* nrm  = (float*)(ob + 20971520);
        int*   idxL = (int*)(ob + 23068672);
        float* valL = (float*)(ob + 24117248);
        // after MP loops, G is dead -> reuse ws:
        float* AdnT = (float*)d_ws;
        int*   idx2 = (int*)((char*)d_ws + ADNT_B);
        float* val2 = (float*)((char*)d_ws + ADNT_B + IDX_B);
        const int chunk = 512;   // z grid (64, 8) -> 512 blocks = exactly 2/CU

        colnorm_kernel<<<WW / 256, 256, 0, stream>>>(Ad, nrm);
        gram_mfma_f64_kernel<<<dim3(WW / 128, WW / 128), 256, 0, stream>>>(Ad, nrm, G);
        mirror_kernel<<<dim3(WW / 64, WW / 64), 256, 0, stream>>>(G);
        for (int r0 = 0; r0 < BBATCH; r0 += chunk) {
            int rows = (BBATCH - r0 < chunk) ? (BBATCH - r0) : chunk;
            z_mfma_f64_kernel<<<dim3(WW / 128, rows / 64), 256, 0, stream>>>(
                x + (size_t)r0 * DD, Ad, bd, nrm, z);
            mp_loop_kernel<<<rows, 256, 0, stream>>>(
                z, G, idxL + (size_t)r0 * KSEL, valL + (size_t)r0 * KSEL);
        }
        {
            int n = BBATCH * KSEL;
            copy_meta_kernel<<<(n + 255) / 256, 256, 0, stream>>>(idxL, valL, idx2, val2, n);
        }
        transpose_scale_kernel<<<dim3(WW / 32, DD / 32), dim3(32, 8), 0, stream>>>(Ad, nrm, AdnT);
        assemble_kernel<<<BBATCH, 256, 0, stream>>>(AdnT, bd, idx2, val2, out, 0);
    }
    // else: ws too small for any fp32-G plan -> leave output zeroed (clean fail)
}

// Round 3
// 4579.168 us; speedup vs baseline: 1.1493x; 1.1493x over previous
//
#include <hip/hip_runtime.h>
#include <cstddef>

// Problem constants (fixed by the reference)
static const int WW = 8192;     // width (atoms)
static const int DD = 768;      // input dim
static const int BBATCH = 8192; // batch
static const int KSEL = 32;     // MP steps

typedef double f64x4 __attribute__((ext_vector_type(4)));

// ---------------------------------------------------------------------------
// Runtime probe of the v_mfma_f64_16x16x4 D-fragment wiring (HW-verified in
// R2: hardcoded map failed, probe-derived map passes). Assumes only the INPUT
// gather (i=lane%16, k=lane/16 for A; j=lane%16, k=lane/16 for B). Decodes
// the (lane,reg)->(i,j) output map for ANY wiring; clamped so a broken
// assumption cannot write OOB. Called at epilogue so pi/pj aren't live
// through the K-loop (register pressure).
// ---------------------------------------------------------------------------
__device__ inline void mfma_f64_probe(int lane, int* pi, int* pj) {
    f64x4 z0{0.0, 0.0, 0.0, 0.0};
    f64x4 d1 = __builtin_amdgcn_mfma_f64_16x16x4f64((double)lane, 1.0, z0, 0, 0, 0);
    f64x4 d2 = __builtin_amdgcn_mfma_f64_16x16x4f64(1.0, (double)lane, z0, 0, 0, 0);
#pragma unroll
    for (int v = 0; v < 4; ++v) {
        pi[v] = (((int)d1[v] - 96) >> 2) & 15;
        pj[v] = (((int)d2[v] - 96) >> 2) & 15;
    }
}

// ---------------------------------------------------------------------------
// column norms of Ad [D, W] -> nrm[W] = max(||Ad[:,w]||, 1e-8), fp64 accumulate
// ---------------------------------------------------------------------------
__global__ __launch_bounds__(256) void colnorm_kernel(const float* __restrict__ Ad,
                                                      float* __restrict__ nrm) {
    int w = blockIdx.x * 256 + threadIdx.x;
    double s = 0.0;
    for (int d = 0; d < DD; ++d) {
        double v = (double)Ad[(size_t)d * WW + w];
        s += v * v;
    }
    nrm[w] = fmaxf((float)sqrt(s), 1e-8f);
}

// ---------------------------------------------------------------------------
// AdnT[w, d] = Ad[d, w] / nrm[w]   (LDS tiled transpose, 32x32)
// ---------------------------------------------------------------------------
__global__ __launch_bounds__(256) void transpose_scale_kernel(const float* __restrict__ Ad,
                                                              const float* __restrict__ nrm,
                                                              float* __restrict__ AdnT) {
    __shared__ float tile[32][33];
    int wb = blockIdx.x * 32;
    int db = blockIdx.y * 32;
    int tx = threadIdx.x;   // 0..31
    int ty = threadIdx.y;   // 0..7
    for (int i = ty; i < 32; i += 8)
        tile[i][tx] = Ad[(size_t)(db + i) * WW + (wb + tx)];
    __syncthreads();
    for (int i = ty; i < 32; i += 8)
        AdnT[(size_t)(wb + i) * DD + (db + tx)] = tile[tx][i] / nrm[wb + i];
}

// ---------------------------------------------------------------------------
// Gram via f64 MFMA: G[i,j] = (sum_d Ad[d,i]*Ad[d,j]) / (nrm[i]*nrm[j])
// R3: 128x64 block (same grid/skip/mirror geometry as the VALU gram), 4 waves
// in 2x2, each wave a 64x32 region = 4x2 tiles of v_mfma_f64_16x16x4 ->
// 64 AGPR accumulator (was 128 in R2 -> 1 wave/SIMD, MfmaUtil 41%).
// __launch_bounds__(256,2) enforces >=2 waves/SIMD so a co-resident block's
// MFMAs cover this block's staging/barrier stalls.
// BK=16; panels staged f32->f64 in LDS (lane-contiguous double2, 0 conflicts
// measured). Next K-panel prefetched into regs before the inner loop.
// ---------------------------------------------------------------------------
__global__ __launch_bounds__(256, 2) void gram_mfma_f64_kernel(const float* __restrict__ Ad,
                                                               const float* __restrict__ nrm,
                                                               float* __restrict__ G) {
    const int bx = blockIdx.x, by = blockIdx.y;
    if (bx < 2 * by) return;   // block entirely strictly-lower -> skip (mirror fills)
    __shared__ __align__(16) double As[16 * 130];   // As[k][i], i=0..127
    __shared__ __align__(16) double Bs[16 * 66];    // Bs[k][j], j=0..63
    const int tid = threadIdx.x;
    const int lane = tid & 63;
    const int wv = tid >> 6;        // wave 0..3
    const int wr = wv >> 1;         // 0..1 row half (64 rows)
    const int wc = wv & 1;          // 0..1 col half (32 cols)
    const int i0 = by * 128;
    const int j0 = bx * 64;
    // A staging: slot q (0..3): row 4q+ar0, pos ap0 (lane-contiguous double2)
    const int ar0 = tid >> 6;        // 0..3
    const int ap0 = (tid & 63) * 2;  // 0..126
    // B staging: rows brow, brow+8; bpos lane-contiguous
    const int brow = tid >> 5;       // 0..7
    const int bpos = (tid & 31) * 2; // 0..62

    f64x4 acc[4][2];
#pragma unroll
    for (int m = 0; m < 4; ++m)
#pragma unroll
        for (int n = 0; n < 2; ++n)
            acc[m][n] = f64x4{0.0, 0.0, 0.0, 0.0};

    float2 aL[4], bl0, bl1;
#pragma unroll
    for (int q = 0; q < 4; ++q)
        aL[q] = *(const float2*)&Ad[(size_t)(4 * q + ar0) * WW + i0 + ap0];
    bl0 = *(const float2*)&Ad[(size_t)(brow) * WW + j0 + bpos];
    bl1 = *(const float2*)&Ad[(size_t)(8 + brow) * WW + j0 + bpos];

    for (int k0 = 0; k0 < DD; k0 += 16) {
        __syncthreads();   // previous iteration's LDS reads done
#pragma unroll
        for (int q = 0; q < 4; ++q) {
            double2 da; da.x = (double)aL[q].x; da.y = (double)aL[q].y;
            *(double2*)&As[(4 * q + ar0) * 130 + ap0] = da;
        }
        {
            double2 d0; d0.x = (double)bl0.x; d0.y = (double)bl0.y;
            double2 d1; d1.x = (double)bl1.x; d1.y = (double)bl1.y;
            *(double2*)&Bs[brow * 66 + bpos] = d0;
            *(double2*)&Bs[(8 + brow) * 66 + bpos] = d1;
        }
        __syncthreads();
        if (k0 + 16 < DD) {   // prefetch next panel; latency hides under MFMAs
#pragma unroll
            for (int q = 0; q < 4; ++q)
                aL[q] = *(const float2*)&Ad[(size_t)(k0 + 16 + 4 * q + ar0) * WW + i0 + ap0];
            bl0 = *(const float2*)&Ad[(size_t)(k0 + 16 + brow) * WW + j0 + bpos];
            bl1 = *(const float2*)&Ad[(size_t)(k0 + 24 + brow) * WW + j0 + bpos];
        }
#pragma unroll
        for (int kc = 0; kc < 4; ++kc) {
            const int krow = kc * 4 + (lane >> 4);
            const double* ap = &As[krow * 130 + wr * 64 + (lane & 15)];
            const double* bp = &Bs[krow * 66 + wc * 32 + (lane & 15)];
            double aF[4], bF[2];
#pragma unroll
            for (int m = 0; m < 4; ++m) aF[m] = ap[m * 16];
#pragma unroll
            for (int n = 0; n < 2; ++n) bF[n] = bp[n * 16];
#pragma unroll
            for (int m = 0; m < 4; ++m)
#pragma unroll
                for (int n = 0; n < 2; ++n)
                    acc[m][n] = __builtin_amdgcn_mfma_f64_16x16x4f64(aF[m], bF[n],
                                                                     acc[m][n], 0, 0, 0);
        }
    }

    int pi[4], pj[4];
    mfma_f64_probe(lane, pi, pj);
#pragma unroll
    for (int m = 0; m < 4; ++m) {
#pragma unroll
        for (int v = 0; v < 4; ++v) {
            int row = i0 + wr * 64 + m * 16 + pi[v];
            double inv_i = 1.0 / (double)nrm[row];
#pragma unroll
            for (int n = 0; n < 2; ++n) {
                int col = j0 + wc * 32 + n * 16 + pj[v];
                G[(size_t)row * WW + col] = (float)(acc[m][n][v] * inv_i / (double)nrm[col]);
            }
        }
    }
}

// ---------------------------------------------------------------------------
// mirror: G[j,i] = G[i,j] for strict-upper 64x64 tiles
// ---------------------------------------------------------------------------
__global__ __launch_bounds__(256) void mirror_kernel(float* __restrict__ G) {
    const int ti = blockIdx.y;
    const int tj = blockIdx.x;
    if (tj <= ti) return;
    __shared__ float tile[64][65];
    const int t = threadIdx.x;
    const int c4 = (t & 15) * 4;   // 0..60
    const int r  = t >> 4;         // 0..15
#pragma unroll
    for (int rr = r; rr < 64; rr += 16) {
        float4 v = *(const float4*)&G[(size_t)(ti * 64 + rr) * WW + tj * 64 + c4];
        tile[rr][c4 + 0] = v.x;
        tile[rr][c4 + 1] = v.y;
        tile[rr][c4 + 2] = v.z;
        tile[rr][c4 + 3] = v.w;
    }
    __syncthreads();
#pragma unroll
    for (int rr = r; rr < 64; rr += 16) {
        float4 v = make_float4(tile[c4 + 0][rr], tile[c4 + 1][rr],
                               tile[c4 + 2][rr], tile[c4 + 3][rr]);
        *(float4*)&G[(size_t)(tj * 64 + rr) * WW + ti * 64 + c4] = v;
    }
}

// ---------------------------------------------------------------------------
// z via f64 MFMA: Z[b,w] = (sum_d (X[b,d]-bd[d]) * Ad[d,w]) / nrm[w]
// 64x128 block, 4 waves (1x4), each wave 4x2 tiles (64 AGPR acc). A staged
// transposed As[k][b] f64 (scalar b64 writes), B staged double2-contiguous.
// Prefetch before the inner loop. f32 bias subtract then exact f64 promote.
// Probe at epilogue. Launch-bounds cap to guarantee >=2 waves/SIMD.
// ---------------------------------------------------------------------------
__global__ __launch_bounds__(256, 2) void z_mfma_f64_kernel(const float* __restrict__ X,
                                                            const float* __restrict__ Ad,
                                                            const float* __restrict__ bd,
                                                            const float* __restrict__ nrm,
                                                            float* __restrict__ Z) {
    __shared__ __align__(16) double As[16 * 66];    // As[k][b], b=0..63
    __shared__ __align__(16) double Bs[16 * 130];   // Bs[k][w], w=0..127
    const int tid = threadIdx.x;
    const int lane = tid & 63;
    const int wc = tid >> 6;        // wave 0..3 -> 32-col group
    const int b0 = blockIdx.y * 64;
    const int w0 = blockIdx.x * 128;
    // A staging: r = tid>>2 (0..63) batch row, k4 = (tid&3)*4 k offset
    const int r  = tid >> 2;
    const int k4 = (tid & 3) * 4;
    // B staging: slot q: row 4q+br0, pos bp0 (lane-contiguous double2)
    const int br0 = tid >> 6;
    const int bp0 = (tid & 63) * 2;

    f64x4 acc[4][2];
#pragma unroll
    for (int m = 0; m < 4; ++m)
#pragma unroll
        for (int n = 0; n < 2; ++n)
            acc[m][n] = f64x4{0.0, 0.0, 0.0, 0.0};

    float4 aL; float2 bL[4];
    {
        float4 bias = *(const float4*)&bd[k4];
        float4 a = *(const float4*)&X[(size_t)(b0 + r) * DD + k4];
        a.x -= bias.x; a.y -= bias.y; a.z -= bias.z; a.w -= bias.w;
        aL = a;
#pragma unroll
        for (int q = 0; q < 4; ++q)
            bL[q] = *(const float2*)&Ad[(size_t)(4 * q + br0) * WW + w0 + bp0];
    }

    for (int k0 = 0; k0 < DD; k0 += 16) {
        __syncthreads();   // previous iteration's LDS reads done
        As[(k4 + 0) * 66 + r] = (double)aL.x;
        As[(k4 + 1) * 66 + r] = (double)aL.y;
        As[(k4 + 2) * 66 + r] = (double)aL.z;
        As[(k4 + 3) * 66 + r] = (double)aL.w;
#pragma unroll
        for (int q = 0; q < 4; ++q) {
            double2 db; db.x = (double)bL[q].x; db.y = (double)bL[q].y;
            *(double2*)&Bs[(4 * q + br0) * 130 + bp0] = db;
        }
        __syncthreads();
        if (k0 + 16 < DD) {
            const int kn = k0 + 16;
            float4 bias = *(const float4*)&bd[kn + k4];
            float4 a = *(const float4*)&X[(size_t)(b0 + r) * DD + kn + k4];
            a.x -= bias.x; a.y -= bias.y; a.z -= bias.z; a.w -= bias.w;
            aL = a;
#pragma unroll
            for (int q = 0; q < 4; ++q)
                bL[q] = *(const float2*)&Ad[(size_t)(kn + 4 * q + br0) * WW + w0 + bp0];
        }
#pragma unroll
        for (int kc = 0; kc < 4; ++kc) {
            const int krow = kc * 4 + (lane >> 4);
            const double* ap = &As[krow * 66 + (lane & 15)];
            const double* bp = &Bs[krow * 130 + wc * 32 + (lane & 15)];
            double aF[4], bF[2];
#pragma unroll
            for (int m = 0; m < 4; ++m) aF[m] = ap[m * 16];
#pragma unroll
            for (int n = 0; n < 2; ++n) bF[n] = bp[n * 16];
#pragma unroll
            for (int m = 0; m < 4; ++m)
#pragma unroll
                for (int n = 0; n < 2; ++n)
                    acc[m][n] = __builtin_amdgcn_mfma_f64_16x16x4f64(aF[m], bF[n],
                                                                     acc[m][n], 0, 0, 0);
        }
    }

    int pi[4], pj[4];
    mfma_f64_probe(lane, pi, pj);
#pragma unroll
    for (int m = 0; m < 4; ++m) {
#pragma unroll
        for (int v = 0; v < 4; ++v) {
            int row = b0 + m * 16 + pi[v];
#pragma unroll
            for (int n = 0; n < 2; ++n) {
                int col = w0 + wc * 32 + n * 16 + pj[v];
                Z[(size_t)row * WW + col] = (float)(acc[m][n][v] / (double)nrm[col]);
            }
        }
    }
}

// ---------------------------------------------------------------------------
// Fused MP loop. One block per batch row; z-row in LDS for all 32 steps.
// ---------------------------------------------------------------------------
__global__ __launch_bounds__(256) void mp_loop_kernel(const float* __restrict__ z0,
                                                      const float* __restrict__ G,
                                                      int* __restrict__ idxL,
                                                      float* __restrict__ valL) {
    __shared__ __align__(16) float zrow[WW];   // 32 KB
    __shared__ float wv[4];
    __shared__ int   wi[4];
    const int b = blockIdx.x;
    const int t = threadIdx.x;
    float4* zs = (float4*)zrow;

    float best = -1.f;
    int bidx = 0;
    unsigned selmask = 0;   // bit j*4+e: slot (t+256*j) element e is selected

    {
        const float4* zp = (const float4*)(z0 + (size_t)b * WW);
#pragma unroll
        for (int j = 0; j < 8; ++j) {
            int slot = t + 256 * j;
            float4 v = zp[slot];
            zs[slot] = v;
            int w = slot * 4;
            float a0 = fabsf(v.x), a1 = fabsf(v.y), a2 = fabsf(v.z), a3 = fabsf(v.w);
            if (a0 > best) { best = a0; bidx = w; }
            if (a1 > best) { best = a1; bidx = w + 1; }
            if (a2 > best) { best = a2; bidx = w + 2; }
            if (a3 > best) { best = a3; bidx = w + 3; }
        }
    }

    for (int k = 0; k < KSEL; ++k) {
        float v = best;
        int i = bidx;
#pragma unroll
        for (int off = 32; off > 0; off >>= 1) {
            float ov = __shfl_xor(v, off, 64);
            int   oi = __shfl_xor(i, off, 64);
            if (ov > v || (ov == v && oi < i)) { v = ov; i = oi; }
        }
        if ((t & 63) == 0) { wv[t >> 6] = v; wi[t >> 6] = i; }
        __syncthreads();   // A: partials visible; prev phase's zrow writes visible
        float rv = wv[0];
        int   ri = wi[0];
#pragma unroll
        for (int q = 1; q < 4; ++q) {
            float qv = wv[q];
            int   qi = wi[q];
            if (qv > rv || (qv == rv && qi < ri)) { rv = qv; ri = qi; }
        }
        const int idx = ri;
        const float val = zrow[idx];   // pre-update value (LDS broadcast)
        if (t == 0) {
            idxL[(size_t)b * KSEL + k] = idx;
            valL[(size_t)b * KSEL + k] = val;
        }
        if (((idx >> 2) & 255) == t)
            selmask |= 1u << (((idx >> 10) << 2) | (idx & 3));
        if (k == KSEL - 1) break;      // final update is dead work
        __syncthreads();   // B: all threads have read val before zrow changes

        best = -1.f;
        bidx = 0;
        const float4* gr = (const float4*)(G + (size_t)idx * WW);
#pragma unroll
        for (int j = 0; j < 8; ++j) {
            int slot = t + 256 * j;
            float4 g = gr[slot];
            float4 z = zs[slot];
            unsigned m = (selmask >> (j * 4)) & 0xFu;
            float n0 = (m & 1u) ? 0.f : z.x - val * g.x;
            float n1 = (m & 2u) ? 0.f : z.y - val * g.y;
            float n2 = (m & 4u) ? 0.f : z.z - val * g.z;
            float n3 = (m & 8u) ? 0.f : z.w - val * g.w;
            zs[slot] = make_float4(n0, n1, n2, n3);
            int w = slot * 4;
            float a0 = fabsf(n0), a1 = fabsf(n1), a2 = fabsf(n2), a3 = fabsf(n3);
            if (a0 > best) { best = a0; bidx = w; }
            if (a1 > best) { best = a1; bidx = w + 1; }
            if (a2 > best) { best = a2; bidx = w + 2; }
            if (a3 > best) { best = a3; bidx = w + 3; }
        }
    }
}

// ---------------------------------------------------------------------------
// copy idx/val metadata (d_out staging -> ws), element-wise
// ---------------------------------------------------------------------------
__global__ __launch_bounds__(256) void copy_meta_kernel(const int* __restrict__ si,
                                                        const float* __restrict__ sv,
                                                        int* __restrict__ di,
                                                        float* __restrict__ dv,
                                                        int n) {
    int i = blockIdx.x * 256 + threadIdx.x;
    if (i < n) {
        di[i] = si[i];
        dv[i] = sv[i];
    }
}

// ---------------------------------------------------------------------------
// out[row, :] = bd + sum_k val[b,k] * AdnT[idx[b,k], :]
// ---------------------------------------------------------------------------
__global__ __launch_bounds__(256) void assemble_kernel(const float* __restrict__ AdnT,
                                                       const float* __restrict__ bd,
                                                       const int* __restrict__ idxL,
                                                       const float* __restrict__ valL,
                                                       float* __restrict__ out,
                                                       int rowStart) {
    __shared__ int sidx[KSEL];
    __shared__ float sval[KSEL];
    const int b = blockIdx.x;
    const int row = rowStart + b;
    const int t = threadIdx.x;
    if (t < KSEL) {
        sidx[t] = idxL[(size_t)b * KSEL + t];
        sval[t] = valL[(size_t)b * KSEL + t];
    }
    __syncthreads();
    float acc0 = bd[t];
    float acc1 = bd[t + 256];
    float acc2 = bd[t + 512];
#pragma unroll 4
    for (int k = 0; k < KSEL; ++k) {
        const float* col = AdnT + (size_t)sidx[k] * DD;
        float v = sval[k];
        acc0 += v * col[t];
        acc1 += v * col[t + 256];
        acc2 += v * col[t + 512];
    }
    out[(size_t)row * DD + t] = acc0;
    out[(size_t)row * DD + t + 256] = acc1;
    out[(size_t)row * DD + t + 512] = acc2;
}

// ---------------------------------------------------------------------------
extern "C" void kernel_launch(void* const* d_in, const int* in_sizes, int n_in,
                              void* d_out, int out_size, void* d_ws, size_t ws_size,
                              hipStream_t stream) {
    const float* x  = (const float*)d_in[0];   // [B, D]
    const float* Ad = (const float*)d_in[1];   // [D, W]
    const float* bd = (const float*)d_in[2];   // [1, D]
    float* out = (float*)d_out;                // [B, D]

    const size_t ADNT_B = (size_t)WW * DD * 4;        // 25,165,824
    const size_t NRM_B  = (size_t)WW * 4;             // 32,768
    const size_t IDX_B  = (size_t)BBATCH * KSEL * 4;  // 1,048,576
    const size_t VAL_B  = IDX_B;
    const size_t G_B    = (size_t)WW * WW * 4;        // 268,435,456 (= 256 MiB)
    const size_t ZROW_B = (size_t)WW * 4;             // 32,768
    const size_t A_MIN  = ADNT_B + NRM_B + IDX_B + VAL_B + G_B + 128 * ZROW_B;

    if (ws_size >= A_MIN) {
        // ---------------- Layout A: everything in ws ----------------
        char* p = (char*)d_ws;
        float* AdnT = (float*)p;  p += ADNT_B;
        float* nrm  = (float*)p;  p += NRM_B;
        int*   idxL = (int*)p;    p += IDX_B;
        float* valL = (float*)p;  p += VAL_B;
        float* G    = (float*)p;  p += G_B;
        float* z    = (float*)p;
        size_t z_avail = ws_size - (ADNT_B + NRM_B + IDX_B + VAL_B + G_B);
        int chunk = (int)((z_avail / ZROW_B) / 128) * 128;
        if (chunk > BBATCH) chunk = BBATCH;

        colnorm_kernel<<<WW / 256, 256, 0, stream>>>(Ad, nrm);
        gram_mfma_f64_kernel<<<dim3(WW / 64, WW / 128), 256, 0, stream>>>(Ad, nrm, G);
        mirror_kernel<<<dim3(WW / 64, WW / 64), 256, 0, stream>>>(G);
        for (int r0 = 0; r0 < BBATCH; r0 += chunk) {
            int rows = (BBATCH - r0 < chunk) ? (BBATCH - r0) : chunk;
            z_mfma_f64_kernel<<<dim3(WW / 128, rows / 64), 256, 0, stream>>>(
                x + (size_t)r0 * DD, Ad, bd, nrm, z);
            mp_loop_kernel<<<rows, 256, 0, stream>>>(
                z, G, idxL + (size_t)r0 * KSEL, valL + (size_t)r0 * KSEL);
        }
        transpose_scale_kernel<<<dim3(WW / 32, DD / 32), dim3(32, 8), 0, stream>>>(Ad, nrm, AdnT);
        assemble_kernel<<<BBATCH, 256, 0, stream>>>(AdnT, bd, idxL, valL, out, 0);
    } else if (ws_size >= G_B) {
        // ---------------- Layout B: ws = G only; scratch in d_out ----------------
        float* G    = (float*)d_ws;
        char*  ob   = (char*)d_out;
        float* z    = (float*)ob;
        float* nrm  = (float*)(ob + 20971520);
        int*   idxL = (int*)(ob + 23068672);
        float* valL = (float*)(ob + 24117248);
        // after MP loops, G is dead -> reuse ws:
        float* AdnT = (float*)d_ws;
        int*   idx2 = (int*)((char*)d_ws + ADNT_B);
        float* val2 = (float*)((char*)d_ws + ADNT_B + IDX_B);
        const int chunk = 512;   // z grid (64, 8) -> 512 blocks

        colnorm_kernel<<<WW / 256, 256, 0, stream>>>(Ad, nrm);
        gram_mfma_f64_kernel<<<dim3(WW / 64, WW / 128), 256, 0, stream>>>(Ad, nrm, G);
        mirror_kernel<<<dim3(WW / 64, WW / 64), 256, 0, stream>>>(G);
        for (int r0 = 0; r0 < BBATCH; r0 += chunk) {
            int rows = (BBATCH - r0 < chunk) ? (BBATCH - r0) : chunk;
            z_mfma_f64_kernel<<<dim3(WW / 128, rows / 64), 256, 0, stream>>>(
                x + (size_t)r0 * DD, Ad, bd, nrm, z);
            mp_loop_kernel<<<rows, 256, 0, stream>>>(
                z, G, idxL + (size_t)r0 * KSEL, valL + (size_t)r0 * KSEL);
        }
        {
            int n = BBATCH * KSEL;
            copy_meta_kernel<<<(n + 255) / 256, 256, 0, stream>>>(idxL, valL, idx2, val2, n);
        }
        transpose_scale_kernel<<<dim3(WW / 32, DD / 32), dim3(32, 8), 0, stream>>>(Ad, nrm, AdnT);
        assemble_kernel<<<BBATCH, 256, 0, stream>>>(AdnT, bd, idx2, val2, out, 0);
    }
    // else: ws too small for any fp32-G plan -> leave output zeroed (clean fail)
}

// Round 4
// 4459.328 us; speedup vs baseline: 1.1802x; 1.0269x over previous
//
#include <hip/hip_runtime.h>
#include <cstddef>

// Problem constants (fixed by the reference)
static const int WW = 8192;     // width (atoms)
static const int DD = 768;      // input dim
static const int BBATCH = 8192; // batch
static const int KSEL = 32;     // MP steps

typedef double f64x4 __attribute__((ext_vector_type(4)));

// ---------------------------------------------------------------------------
// Runtime probe of the v_mfma_f64_16x16x4 D-fragment wiring (HW-verified in
// R2: hardcoded map failed, probe-derived map passes). Assumes only the INPUT
// gather (i=lane%16, k=lane/16 for A; j=lane%16, k=lane/16 for B). Decodes
// the (lane,reg)->(i,j) output map for ANY wiring; clamped so a broken
// assumption cannot write OOB. Called at epilogue so pi/pj aren't live
// through the K-loop (register pressure).
// ---------------------------------------------------------------------------
__device__ inline void mfma_f64_probe(int lane, int* pi, int* pj) {
    f64x4 z0{0.0, 0.0, 0.0, 0.0};
    f64x4 d1 = __builtin_amdgcn_mfma_f64_16x16x4f64((double)lane, 1.0, z0, 0, 0, 0);
    f64x4 d2 = __builtin_amdgcn_mfma_f64_16x16x4f64(1.0, (double)lane, z0, 0, 0, 0);
#pragma unroll
    for (int v = 0; v < 4; ++v) {
        pi[v] = (((int)d1[v] - 96) >> 2) & 15;
        pj[v] = (((int)d2[v] - 96) >> 2) & 15;
    }
}

// ---------------------------------------------------------------------------
// column norms of Ad [D, W] -> nrm[W] = max(||Ad[:,w]||, 1e-8), fp64 accumulate
// ---------------------------------------------------------------------------
__global__ __launch_bounds__(256) void colnorm_kernel(const float* __restrict__ Ad,
                                                      float* __restrict__ nrm) {
    int w = blockIdx.x * 256 + threadIdx.x;
    double s = 0.0;
    for (int d = 0; d < DD; ++d) {
        double v = (double)Ad[(size_t)d * WW + w];
        s += v * v;
    }
    nrm[w] = fmaxf((float)sqrt(s), 1e-8f);
}

// ---------------------------------------------------------------------------
// AdnT[w, d] = Ad[d, w] / nrm[w]   (LDS tiled transpose, 32x32)
// ---------------------------------------------------------------------------
__global__ __launch_bounds__(256) void transpose_scale_kernel(const float* __restrict__ Ad,
                                                              const float* __restrict__ nrm,
                                                              float* __restrict__ AdnT) {
    __shared__ float tile[32][33];
    int wb = blockIdx.x * 32;
    int db = blockIdx.y * 32;
    int tx = threadIdx.x;   // 0..31
    int ty = threadIdx.y;   // 0..7
    for (int i = ty; i < 32; i += 8)
        tile[i][tx] = Ad[(size_t)(db + i) * WW + (wb + tx)];
    __syncthreads();
    for (int i = ty; i < 32; i += 8)
        AdnT[(size_t)(wb + i) * DD + (db + tx)] = tile[tx][i] / nrm[wb + i];
}

// ---------------------------------------------------------------------------
// Gram via f64 MFMA: G[i,j] = (sum_d Ad[d,i]*Ad[d,j]) / (nrm[i]*nrm[j])
// R4: BK 16 -> 32. Each K-step now carries 64 MFMAs/wave (4096 matrix-pipe
// cycles) across the same 2-barrier staging cadence -> barrier/staging serial
// segment amortized 2x (R3 measured: MfmaUtil 65%, idle = barrier cadence).
// 128x64 block, 4 waves 2x2, each wave 64x32 = 4x2 tiles (64-reg f64 acc).
// LDS 50 KiB/block (As 32x130 + Bs 32x66 dbl) -> 2-3 blocks/CU still fit.
// Panels staged f32->f64, lane-contiguous double2 (0 conflicts measured).
// Next K-panel prefetched into regs before the MFMA phase.
// Upper blocks only (bx >= 2*by); mirror fills strict-lower tiles.
// ---------------------------------------------------------------------------
__global__ __launch_bounds__(256, 2) void gram_mfma_f64_kernel(const float* __restrict__ Ad,
                                                               const float* __restrict__ nrm,
                                                               float* __restrict__ G) {
    const int bx = blockIdx.x, by = blockIdx.y;
    if (bx < 2 * by) return;   // block entirely strictly-lower -> skip (mirror fills)
    __shared__ __align__(16) double As[32 * 130];   // As[k][i], i=0..127
    __shared__ __align__(16) double Bs[32 * 66];    // Bs[k][j], j=0..63
    const int tid = threadIdx.x;
    const int lane = tid & 63;
    const int wv = tid >> 6;        // wave 0..3
    const int wr = wv >> 1;         // 0..1 row half (64 rows)
    const int wc = wv & 1;          // 0..1 col half (32 cols)
    const int i0 = by * 128;
    const int j0 = bx * 64;
    // A staging: slot q (0..7): row 4q+ar0, pos ap0 (lane-contiguous double2)
    const int ar0 = tid >> 6;        // 0..3
    const int ap0 = (tid & 63) * 2;  // 0..126
    // B staging: slot s (0..3): row 8s+brow; bpos lane-contiguous
    const int brow = tid >> 5;       // 0..7
    const int bpos = (tid & 31) * 2; // 0..62

    f64x4 acc[4][2];
#pragma unroll
    for (int m = 0; m < 4; ++m)
#pragma unroll
        for (int n = 0; n < 2; ++n)
            acc[m][n] = f64x4{0.0, 0.0, 0.0, 0.0};

    float2 aL[8], bl[4];
#pragma unroll
    for (int q = 0; q < 8; ++q)
        aL[q] = *(const float2*)&Ad[(size_t)(4 * q + ar0) * WW + i0 + ap0];
#pragma unroll
    for (int s = 0; s < 4; ++s)
        bl[s] = *(const float2*)&Ad[(size_t)(8 * s + brow) * WW + j0 + bpos];

    for (int k0 = 0; k0 < DD; k0 += 32) {
        __syncthreads();   // previous iteration's LDS reads done
#pragma unroll
        for (int q = 0; q < 8; ++q) {
            double2 da; da.x = (double)aL[q].x; da.y = (double)aL[q].y;
            *(double2*)&As[(4 * q + ar0) * 130 + ap0] = da;
        }
#pragma unroll
        for (int s = 0; s < 4; ++s) {
            double2 d0; d0.x = (double)bl[s].x; d0.y = (double)bl[s].y;
            *(double2*)&Bs[(8 * s + brow) * 66 + bpos] = d0;
        }
        __syncthreads();
        if (k0 + 32 < DD) {   // prefetch next panel; latency hides under MFMAs
#pragma unroll
            for (int q = 0; q < 8; ++q)
                aL[q] = *(const float2*)&Ad[(size_t)(k0 + 32 + 4 * q + ar0) * WW + i0 + ap0];
#pragma unroll
            for (int s = 0; s < 4; ++s)
                bl[s] = *(const float2*)&Ad[(size_t)(k0 + 32 + 8 * s + brow) * WW + j0 + bpos];
        }
#pragma unroll
        for (int kc = 0; kc < 8; ++kc) {
            const int krow = kc * 4 + (lane >> 4);
            const double* ap = &As[krow * 130 + wr * 64 + (lane & 15)];
            const double* bp = &Bs[krow * 66 + wc * 32 + (lane & 15)];
            double aF[4], bF[2];
#pragma unroll
            for (int m = 0; m < 4; ++m) aF[m] = ap[m * 16];
#pragma unroll
            for (int n = 0; n < 2; ++n) bF[n] = bp[n * 16];
#pragma unroll
            for (int m = 0; m < 4; ++m)
#pragma unroll
                for (int n = 0; n < 2; ++n)
                    acc[m][n] = __builtin_amdgcn_mfma_f64_16x16x4f64(aF[m], bF[n],
                                                                     acc[m][n], 0, 0, 0);
        }
    }

    int pi[4], pj[4];
    mfma_f64_probe(lane, pi, pj);
#pragma unroll
    for (int m = 0; m < 4; ++m) {
#pragma unroll
        for (int v = 0; v < 4; ++v) {
            int row = i0 + wr * 64 + m * 16 + pi[v];
            double inv_i = 1.0 / (double)nrm[row];
#pragma unroll
            for (int n = 0; n < 2; ++n) {
                int col = j0 + wc * 32 + n * 16 + pj[v];
                G[(size_t)row * WW + col] = (float)(acc[m][n][v] * inv_i / (double)nrm[col]);
            }
        }
    }
}

// ---------------------------------------------------------------------------
// mirror: G[j,i] = G[i,j] for strict-upper 64x64 tiles
// ---------------------------------------------------------------------------
__global__ __launch_bounds__(256) void mirror_kernel(float* __restrict__ G) {
    const int ti = blockIdx.y;
    const int tj = blockIdx.x;
    if (tj <= ti) return;
    __shared__ float tile[64][65];
    const int t = threadIdx.x;
    const int c4 = (t & 15) * 4;   // 0..60
    const int r  = t >> 4;         // 0..15
#pragma unroll
    for (int rr = r; rr < 64; rr += 16) {
        float4 v = *(const float4*)&G[(size_t)(ti * 64 + rr) * WW + tj * 64 + c4];
        tile[rr][c4 + 0] = v.x;
        tile[rr][c4 + 1] = v.y;
        tile[rr][c4 + 2] = v.z;
        tile[rr][c4 + 3] = v.w;
    }
    __syncthreads();
#pragma unroll
    for (int rr = r; rr < 64; rr += 16) {
        float4 v = make_float4(tile[c4 + 0][rr], tile[c4 + 1][rr],
                               tile[c4 + 2][rr], tile[c4 + 3][rr]);
        *(float4*)&G[(size_t)(tj * 64 + rr) * WW + ti * 64 + c4] = v;
    }
}

// ---------------------------------------------------------------------------
// z via f64 MFMA: Z[b,w] = (sum_d (X[b,d]-bd[d]) * Ad[d,w]) / nrm[w]
// R4: BK 16 -> 32 (same amortization as gram). 64x128 block, 4 waves (1x4),
// each wave 4x2 tiles. A staged transposed As[k][b] f64 (scalar b64 writes,
// <=2-way banks = free), B staged double2-contiguous. Prefetch before MFMA
// phase. f32 bias subtract then exact f64 promote (matches reference).
// Per-element k-order unchanged vs R3 (same FMA chain; only barrier cadence
// differs) -> bitwise-identical Z.
// ---------------------------------------------------------------------------
__global__ __launch_bounds__(256, 2) void z_mfma_f64_kernel(const float* __restrict__ X,
                                                            const float* __restrict__ Ad,
                                                            const float* __restrict__ bd,
                                                            const float* __restrict__ nrm,
                                                            float* __restrict__ Z) {
    __shared__ __align__(16) double As[32 * 66];    // As[k][b], b=0..63
    __shared__ __align__(16) double Bs[32 * 130];   // Bs[k][w], w=0..127
    const int tid = threadIdx.x;
    const int lane = tid & 63;
    const int wc = tid >> 6;        // wave 0..3 -> 32-col group
    const int b0 = blockIdx.y * 64;
    const int w0 = blockIdx.x * 128;
    // A staging: r = tid>>2 (0..63) batch row, k8 = (tid&3)*8 k offset (0..24)
    const int r  = tid >> 2;
    const int k8 = (tid & 3) * 8;
    // B staging: slot q (0..7): row 4q+br0, pos bp0 (lane-contiguous double2)
    const int br0 = tid >> 6;
    const int bp0 = (tid & 63) * 2;

    f64x4 acc[4][2];
#pragma unroll
    for (int m = 0; m < 4; ++m)
#pragma unroll
        for (int n = 0; n < 2; ++n)
            acc[m][n] = f64x4{0.0, 0.0, 0.0, 0.0};

    float4 a0L, a1L; float2 bL[8];
    {
        float4 bias0 = *(const float4*)&bd[k8];
        float4 bias1 = *(const float4*)&bd[k8 + 4];
        float4 a0 = *(const float4*)&X[(size_t)(b0 + r) * DD + k8];
        float4 a1 = *(const float4*)&X[(size_t)(b0 + r) * DD + k8 + 4];
        a0.x -= bias0.x; a0.y -= bias0.y; a0.z -= bias0.z; a0.w -= bias0.w;
        a1.x -= bias1.x; a1.y -= bias1.y; a1.z -= bias1.z; a1.w -= bias1.w;
        a0L = a0; a1L = a1;
#pragma unroll
        for (int q = 0; q < 8; ++q)
            bL[q] = *(const float2*)&Ad[(size_t)(4 * q + br0) * WW + w0 + bp0];
    }

    for (int k0 = 0; k0 < DD; k0 += 32) {
        __syncthreads();   // previous iteration's LDS reads done
        As[(k8 + 0) * 66 + r] = (double)a0L.x;
        As[(k8 + 1) * 66 + r] = (double)a0L.y;
        As[(k8 + 2) * 66 + r] = (double)a0L.z;
        As[(k8 + 3) * 66 + r] = (double)a0L.w;
        As[(k8 + 4) * 66 + r] = (double)a1L.x;
        As[(k8 + 5) * 66 + r] = (double)a1L.y;
        As[(k8 + 6) * 66 + r] = (double)a1L.z;
        As[(k8 + 7) * 66 + r] = (double)a1L.w;
#pragma unroll
        for (int q = 0; q < 8; ++q) {
            double2 db; db.x = (double)bL[q].x; db.y = (double)bL[q].y;
            *(double2*)&Bs[(4 * q + br0) * 130 + bp0] = db;
        }
        __syncthreads();
        if (k0 + 32 < DD) {
            const int kn = k0 + 32;
            float4 bias0 = *(const float4*)&bd[kn + k8];
            float4 bias1 = *(const float4*)&bd[kn + k8 + 4];
            float4 a0 = *(const float4*)&X[(size_t)(b0 + r) * DD + kn + k8];
            float4 a1 = *(const float4*)&X[(size_t)(b0 + r) * DD + kn + k8 + 4];
            a0.x -= bias0.x; a0.y -= bias0.y; a0.z -= bias0.z; a0.w -= bias0.w;
            a1.x -= bias1.x; a1.y -= bias1.y; a1.z -= bias1.z; a1.w -= bias1.w;
            a0L = a0; a1L = a1;
#pragma unroll
            for (int q = 0; q < 8; ++q)
                bL[q] = *(const float2*)&Ad[(size_t)(kn + 4 * q + br0) * WW + w0 + bp0];
        }
#pragma unroll
        for (int kc = 0; kc < 8; ++kc) {
            const int krow = kc * 4 + (lane >> 4);
            const double* ap = &As[krow * 66 + (lane & 15)];
            const double* bp = &Bs[krow * 130 + wc * 32 + (lane & 15)];
            double aF[4], bF[2];
#pragma unroll
            for (int m = 0; m < 4; ++m) aF[m] = ap[m * 16];
#pragma unroll
            for (int n = 0; n < 2; ++n) bF[n] = bp[n * 16];
#pragma unroll
            for (int m = 0; m < 4; ++m)
#pragma unroll
                for (int n = 0; n < 2; ++n)
                    acc[m][n] = __builtin_amdgcn_mfma_f64_16x16x4f64(aF[m], bF[n],
                                                                     acc[m][n], 0, 0, 0);
        }
    }

    int pi[4], pj[4];
    mfma_f64_probe(lane, pi, pj);
#pragma unroll
    for (int m = 0; m < 4; ++m) {
#pragma unroll
        for (int v = 0; v < 4; ++v) {
            int row = b0 + m * 16 + pi[v];
#pragma unroll
            for (int n = 0; n < 2; ++n) {
                int col = w0 + wc * 32 + n * 16 + pj[v];
                Z[(size_t)row * WW + col] = (float)(acc[m][n][v] / (double)nrm[col]);
            }
        }
    }
}

// ---------------------------------------------------------------------------
// Fused MP loop. One block per batch row; z-row in LDS for all 32 steps.
// ---------------------------------------------------------------------------
__global__ __launch_bounds__(256) void mp_loop_kernel(const float* __restrict__ z0,
                                                      const float* __restrict__ G,
                                                      int* __restrict__ idxL,
                                                      float* __restrict__ valL) {
    __shared__ __align__(16) float zrow[WW];   // 32 KB
    __shared__ float wv[4];
    __shared__ int   wi[4];
    const int b = blockIdx.x;
    const int t = threadIdx.x;
    float4* zs = (float4*)zrow;

    float best = -1.f;
    int bidx = 0;
    unsigned selmask = 0;   // bit j*4+e: slot (t+256*j) element e is selected

    {
        const float4* zp = (const float4*)(z0 + (size_t)b * WW);
#pragma unroll
        for (int j = 0; j < 8; ++j) {
            int slot = t + 256 * j;
            float4 v = zp[slot];
            zs[slot] = v;
            int w = slot * 4;
            float a0 = fabsf(v.x), a1 = fabsf(v.y), a2 = fabsf(v.z), a3 = fabsf(v.w);
            if (a0 > best) { best = a0; bidx = w; }
            if (a1 > best) { best = a1; bidx = w + 1; }
            if (a2 > best) { best = a2; bidx = w + 2; }
            if (a3 > best) { best = a3; bidx = w + 3; }
        }
    }

    for (int k = 0; k < KSEL; ++k) {
        float v = best;
        int i = bidx;
#pragma unroll
        for (int off = 32; off > 0; off >>= 1) {
            float ov = __shfl_xor(v, off, 64);
            int   oi = __shfl_xor(i, off, 64);
            if (ov > v || (ov == v && oi < i)) { v = ov; i = oi; }
        }
        if ((t & 63) == 0) { wv[t >> 6] = v; wi[t >> 6] = i; }
        __syncthreads();   // A: partials visible; prev phase's zrow writes visible
        float rv = wv[0];
        int   ri = wi[0];
#pragma unroll
        for (int q = 1; q < 4; ++q) {
            float qv = wv[q];
            int   qi = wi[q];
            if (qv > rv || (qv == rv && qi < ri)) { rv = qv; ri = qi; }
        }
        const int idx = ri;
        const float val = zrow[idx];   // pre-update value (LDS broadcast)
        if (t == 0) {
            idxL[(size_t)b * KSEL + k] = idx;
            valL[(size_t)b * KSEL + k] = val;
        }
        if (((idx >> 2) & 255) == t)
            selmask |= 1u << (((idx >> 10) << 2) | (idx & 3));
        if (k == KSEL - 1) break;      // final update is dead work
        __syncthreads();   // B: all threads have read val before zrow changes

        best = -1.f;
        bidx = 0;
        const float4* gr = (const float4*)(G + (size_t)idx * WW);
#pragma unroll
        for (int j = 0; j < 8; ++j) {
            int slot = t + 256 * j;
            float4 g = gr[slot];
            float4 z = zs[slot];
            unsigned m = (selmask >> (j * 4)) & 0xFu;
            float n0 = (m & 1u) ? 0.f : z.x - val * g.x;
            float n1 = (m & 2u) ? 0.f : z.y - val * g.y;
            float n2 = (m & 4u) ? 0.f : z.z - val * g.z;
            float n3 = (m & 8u) ? 0.f : z.w - val * g.w;
            zs[slot] = make_float4(n0, n1, n2, n3);
            int w = slot * 4;
            float a0 = fabsf(n0), a1 = fabsf(n1), a2 = fabsf(n2), a3 = fabsf(n3);
            if (a0 > best) { best = a0; bidx = w; }
            if (a1 > best) { best = a1; bidx = w + 1; }
            if (a2 > best) { best = a2; bidx = w + 2; }
            if (a3 > best) { best = a3; bidx = w + 3; }
        }
    }
}

// ---------------------------------------------------------------------------
// copy idx/val metadata (d_out staging -> ws), element-wise
// ---------------------------------------------------------------------------
__global__ __launch_bounds__(256) void copy_meta_kernel(const int* __restrict__ si,
                                                        const float* __restrict__ sv,
                                                        int* __restrict__ di,
                                                        float* __restrict__ dv,
                                                        int n) {
    int i = blockIdx.x * 256 + threadIdx.x;
    if (i < n) {
        di[i] = si[i];
        dv[i] = sv[i];
    }
}

// ---------------------------------------------------------------------------
// out[row, :] = bd + sum_k val[b,k] * AdnT[idx[b,k], :]
// ---------------------------------------------------------------------------
__global__ __launch_bounds__(256) void assemble_kernel(const float* __restrict__ AdnT,
                                                       const float* __restrict__ bd,
                                                       const int* __restrict__ idxL,
                                                       const float* __restrict__ valL,
                                                       float* __restrict__ out,
                                                       int rowStart) {
    __shared__ int sidx[KSEL];
    __shared__ float sval[KSEL];
    const int b = blockIdx.x;
    const int row = rowStart + b;
    const int t = threadIdx.x;
    if (t < KSEL) {
        sidx[t] = idxL[(size_t)b * KSEL + t];
        sval[t] = valL[(size_t)b * KSEL + t];
    }
    __syncthreads();
    float acc0 = bd[t];
    float acc1 = bd[t + 256];
    float acc2 = bd[t + 512];
#pragma unroll 4
    for (int k = 0; k < KSEL; ++k) {
        const float* col = AdnT + (size_t)sidx[k] * DD;
        float v = sval[k];
        acc0 += v * col[t];
        acc1 += v * col[t + 256];
        acc2 += v * col[t + 512];
    }
    out[(size_t)row * DD + t] = acc0;
    out[(size_t)row * DD + t + 256] = acc1;
    out[(size_t)row * DD + t + 512] = acc2;
}

// ---------------------------------------------------------------------------
extern "C" void kernel_launch(void* const* d_in, const int* in_sizes, int n_in,
                              void* d_out, int out_size, void* d_ws, size_t ws_size,
                              hipStream_t stream) {
    const float* x  = (const float*)d_in[0];   // [B, D]
    const float* Ad = (const float*)d_in[1];   // [D, W]
    const float* bd = (const float*)d_in[2];   // [1, D]
    float* out = (float*)d_out;                // [B, D]

    const size_t ADNT_B = (size_t)WW * DD * 4;        // 25,165,824
    const size_t NRM_B  = (size_t)WW * 4;             // 32,768
    const size_t IDX_B  = (size_t)BBATCH * KSEL * 4;  // 1,048,576
    const size_t VAL_B  = IDX_B;
    const size_t G_B    = (size_t)WW * WW * 4;        // 268,435,456 (= 256 MiB)
    const size_t ZROW_B = (size_t)WW * 4;             // 32,768
    const size_t A_MIN  = ADNT_B + NRM_B + IDX_B + VAL_B + G_B + 128 * ZROW_B;

    if (ws_size >= A_MIN) {
        // ---------------- Layout A: everything in ws ----------------
        char* p = (char*)d_ws;
        float* AdnT = (float*)p;  p += ADNT_B;
        float* nrm  = (float*)p;  p += NRM_B;
        int*   idxL = (int*)p;    p += IDX_B;
        float* valL = (float*)p;  p += VAL_B;
        float* G    = (float*)p;  p += G_B;
        float* z    = (float*)p;
        size_t z_avail = ws_size - (ADNT_B + NRM_B + IDX_B + VAL_B + G_B);
        int chunk = (int)((z_avail / ZROW_B) / 128) * 128;
        if (chunk > BBATCH) chunk = BBATCH;

        colnorm_kernel<<<WW / 256, 256, 0, stream>>>(Ad, nrm);
        gram_mfma_f64_kernel<<<dim3(WW / 64, WW / 128), 256, 0, stream>>>(Ad, nrm, G);
        mirror_kernel<<<dim3(WW / 64, WW / 64), 256, 0, stream>>>(G);
        for (int r0 = 0; r0 < BBATCH; r0 += chunk) {
            int rows = (BBATCH - r0 < chunk) ? (BBATCH - r0) : chunk;
            z_mfma_f64_kernel<<<dim3(WW / 128, rows / 64), 256, 0, stream>>>(
                x + (size_t)r0 * DD, Ad, bd, nrm, z);
            mp_loop_kernel<<<rows, 256, 0, stream>>>(
                z, G, idxL + (size_t)r0 * KSEL, valL + (size_t)r0 * KSEL);
        }
        transpose_scale_kernel<<<dim3(WW / 32, DD / 32), dim3(32, 8), 0, stream>>>(Ad, nrm, AdnT);
        assemble_kernel<<<BBATCH, 256, 0, stream>>>(AdnT, bd, idxL, valL, out, 0);
    } else if (ws_size >= G_B) {
        // ---------------- Layout B: ws = G only; scratch in d_out ----------------
        float* G    = (float*)d_ws;
        char*  ob   = (char*)d_out;
        float* z    = (float*)ob;
        float* nrm  = (float*)(ob + 20971520);
        int*   idxL = (int*)(ob + 23068672);
        float* valL = (float*)(ob + 24117248);
        // after MP loops, G is dead -> reuse ws:
        float* AdnT = (float*)d_ws;
        int*   idx2 = (int*)((char*)d_ws + ADNT_B);
        float* val2 = (float*)((char*)d_ws + ADNT_B + IDX_B);
        const int chunk = 512;   // z grid (64, 8) -> 512 blocks

        colnorm_kernel<<<WW / 256, 256, 0, stream>>>(Ad, nrm);
        gram_mfma_f64_kernel<<<dim3(WW / 64, WW / 128), 256, 0, stream>>>(Ad, nrm, G);
        mirror_kernel<<<dim3(WW / 64, WW / 64), 256, 0, stream>>>(G);
        for (int r0 = 0; r0 < BBATCH; r0 += chunk) {
            int rows = (BBATCH - r0 < chunk) ? (BBATCH - r0) : chunk;
            z_mfma_f64_kernel<<<dim3(WW / 128, rows / 64), 256, 0, stream>>>(
                x + (size_t)r0 * DD, Ad, bd, nrm, z);
            mp_loop_kernel<<<rows, 256, 0, stream>>>(
                z, G, idxL + (size_t)r0 * KSEL, valL + (size_t)r0 * KSEL);
        }
        {
            int n = BBATCH * KSEL;
            copy_meta_kernel<<<(n + 255) / 256, 256, 0, stream>>>(idxL, valL, idx2, val2, n);
        }
        transpose_scale_kernel<<<dim3(WW / 32, DD / 32), dim3(32, 8), 0, stream>>>(Ad, nrm, AdnT);
        assemble_kernel<<<BBATCH, 256, 0, stream>>>(AdnT, bd, idx2, val2, out, 0);
    }
    // else: ws too small for any fp32-G plan -> leave output zeroed (clean fail)
}